// Round 1
// baseline (640.433 us; speedup 1.0000x reference)
//
#include <hip/hip_runtime.h>

// FiberBundleEmbedding: base/conn/generator gathers + Newton-Schulz polar
// decomposition of 32768 near-identity 32x32 matrices (replaces SVD).
//
// Shapes: tokens[8][4096] i32; base_w[50257][512] f32; fiber_w[50257][1024] f32;
// conn_w[50257][8] f32; generators[8][32][32] f32.
// Out (f32, concat): base 16777216 | fiber 33554432 | conn 262144 | gen 8192.

#define NMAT   32768      // B*S
#define NITER  5          // Newton-Schulz iterations (e0~0.14 -> ~1e-11)

// LDS addressing: row stride 36 floats (16B-aligned rows) plus a
// row-group offset 4*((row>>2)&7) so matmul1's 8 row-group reads hit
// 8 distinct bank quads (conflict-free); matmul2 rows are per-k uniform.
__device__ __forceinline__ int ldsoff(int row, int col) {
    return row * 36 + (((row >> 2) & 7) << 2) + col;
}
#define LDS_FLOATS (32 * 36 + 32)

__global__ __launch_bounds__(64) void polar_kernel(
    const int* __restrict__ tokens,
    const float* __restrict__ fiber_w,
    float* __restrict__ out_fiber)
{
    __shared__ float Xa[LDS_FLOATS];
    __shared__ float Xb[LDS_FLOATS];
    __shared__ float Mm[LDS_FLOATS];

    const int t   = threadIdx.x;           // 0..63
    const int mat = blockIdx.x;            // 0..32767
    const int tok = tokens[mat];
    const float* src = fiber_w + (size_t)tok * 1024;

    // ---- load 32x32 matrix into LDS (coalesced float4) ----
    #pragma unroll
    for (int it = 0; it < 4; ++it) {
        int c   = t + 64 * it;             // float4 chunk 0..255
        int row = c >> 3;
        int col = (c & 7) << 2;
        float4 v = reinterpret_cast<const float4*>(src)[c];
        *reinterpret_cast<float4*>(&Xa[ldsoff(row, col)]) = v;
    }
    __syncthreads();

    const int tg  = t >> 3;                // tile row group 0..7
    const int tb  = t & 7;                 // tile col group 0..7
    const int ta4 = tg << 2;               // row base i0
    const int tb4 = tb << 2;               // col base j0

    float* Xcur = Xa;
    float* Xnxt = Xb;

    for (int iter = 0; iter < NITER; ++iter) {
        // ---- matmul1: M = 1.5 I - 0.5 * X X^T  (P symmetric) ----
        float acc[4][4];
        #pragma unroll
        for (int r = 0; r < 4; ++r)
            #pragma unroll
            for (int c = 0; c < 4; ++c) acc[r][c] = 0.f;

        #pragma unroll
        for (int k = 0; k < 32; k += 4) {
            float4 ar[4], br[4];
            #pragma unroll
            for (int r = 0; r < 4; ++r)
                ar[r] = *reinterpret_cast<const float4*>(&Xcur[ldsoff(ta4 + r, k)]);
            #pragma unroll
            for (int c = 0; c < 4; ++c)
                br[c] = *reinterpret_cast<const float4*>(&Xcur[ldsoff(tb4 + c, k)]);
            #pragma unroll
            for (int r = 0; r < 4; ++r)
                #pragma unroll
                for (int c = 0; c < 4; ++c) {
                    acc[r][c] += ar[r].x * br[c].x;
                    acc[r][c] += ar[r].y * br[c].y;
                    acc[r][c] += ar[r].z * br[c].z;
                    acc[r][c] += ar[r].w * br[c].w;
                }
        }
        // write M = 1.5I - 0.5P for this tile
        #pragma unroll
        for (int r = 0; r < 4; ++r) {
            float4 m;
            m.x = -0.5f * acc[r][0];
            m.y = -0.5f * acc[r][1];
            m.z = -0.5f * acc[r][2];
            m.w = -0.5f * acc[r][3];
            if (tg == tb) {   // diagonal tile
                if      (r == 0) m.x += 1.5f;
                else if (r == 1) m.y += 1.5f;
                else if (r == 2) m.z += 1.5f;
                else             m.w += 1.5f;
            }
            *reinterpret_cast<float4*>(&Mm[ldsoff(ta4 + r, tb4)]) = m;
        }
        __syncthreads();

        // ---- matmul2: Y = M X, using M symmetric: Y[i][j] = sum_k M[k][i] X[k][j] ----
        #pragma unroll
        for (int r = 0; r < 4; ++r)
            #pragma unroll
            for (int c = 0; c < 4; ++c) acc[r][c] = 0.f;

        #pragma unroll
        for (int k = 0; k < 32; ++k) {
            float4 mv = *reinterpret_cast<const float4*>(&Mm[ldsoff(k, ta4)]);
            float4 xv = *reinterpret_cast<const float4*>(&Xcur[ldsoff(k, tb4)]);
            acc[0][0] += mv.x * xv.x; acc[0][1] += mv.x * xv.y;
            acc[0][2] += mv.x * xv.z; acc[0][3] += mv.x * xv.w;
            acc[1][0] += mv.y * xv.x; acc[1][1] += mv.y * xv.y;
            acc[1][2] += mv.y * xv.z; acc[1][3] += mv.y * xv.w;
            acc[2][0] += mv.z * xv.x; acc[2][1] += mv.z * xv.y;
            acc[2][2] += mv.z * xv.z; acc[2][3] += mv.z * xv.w;
            acc[3][0] += mv.w * xv.x; acc[3][1] += mv.w * xv.y;
            acc[3][2] += mv.w * xv.z; acc[3][3] += mv.w * xv.w;
        }

        if (iter < NITER - 1) {
            #pragma unroll
            for (int r = 0; r < 4; ++r) {
                float4 y;
                y.x = acc[r][0]; y.y = acc[r][1]; y.z = acc[r][2]; y.w = acc[r][3];
                *reinterpret_cast<float4*>(&Xnxt[ldsoff(ta4 + r, tb4)]) = y;
            }
            __syncthreads();
            float* tmp = Xcur; Xcur = Xnxt; Xnxt = tmp;
        } else {
            // final iteration: write straight to global
            float* dst = out_fiber + (size_t)mat * 1024;
            #pragma unroll
            for (int r = 0; r < 4; ++r) {
                float4 y;
                y.x = acc[r][0]; y.y = acc[r][1]; y.z = acc[r][2]; y.w = acc[r][3];
                *reinterpret_cast<float4*>(&dst[(ta4 + r) * 32 + tb4]) = y;
            }
        }
    }
}

// base / connection gathers + generators passthrough, all float4-vectorized.
__global__ __launch_bounds__(256) void gather_kernel(
    const int*    __restrict__ tokens,
    const float4* __restrict__ base_w,   // rows of 128 float4
    const float4* __restrict__ conn_w,   // rows of 2 float4
    const float4* __restrict__ gens,     // 2048 float4
    float4*       __restrict__ out)
{
    const int NB = NMAT * 128;           // 4194304 float4 of base
    const int NC = NMAT * 2;             // 65536 float4 of conn
    const int NG = 2048;                 // generators float4
    const int total = NB + NC + NG;
    const int CONN_OFF = 12582912;       // (16777216+33554432)/4
    const int GEN_OFF  = 12648448;       // 50593792/4

    for (int i = blockIdx.x * blockDim.x + threadIdx.x; i < total;
         i += gridDim.x * blockDim.x) {
        if (i < NB) {
            int row = i >> 7, c = i & 127;
            out[i] = base_w[(size_t)tokens[row] * 128 + c];
        } else if (i < NB + NC) {
            int j = i - NB;
            int row = j >> 1, c = j & 1;
            out[CONN_OFF + j] = conn_w[(size_t)tokens[row] * 2 + c];
        } else {
            int j = i - NB - NC;
            out[GEN_OFF + j] = gens[j];
        }
    }
}

extern "C" void kernel_launch(void* const* d_in, const int* in_sizes, int n_in,
                              void* d_out, int out_size, void* d_ws, size_t ws_size,
                              hipStream_t stream) {
    const int*   tokens  = (const int*)  d_in[0];
    const float* base_w  = (const float*)d_in[1];
    const float* fiber_w = (const float*)d_in[2];
    const float* conn_w  = (const float*)d_in[3];
    const float* gens    = (const float*)d_in[4];
    float* out = (float*)d_out;

    polar_kernel<<<NMAT, 64, 0, stream>>>(tokens, fiber_w, out + 16777216);
    gather_kernel<<<2048, 256, 0, stream>>>(
        tokens,
        reinterpret_cast<const float4*>(base_w),
        reinterpret_cast<const float4*>(conn_w),
        reinterpret_cast<const float4*>(gens),
        reinterpret_cast<float4*>(out));
}

// Round 2
// 425.429 us; speedup vs baseline: 1.5054x; 1.5054x over previous
//
#include <hip/hip_runtime.h>

// FiberBundleEmbedding on gfx950.
// fiber: polar factor of 32768 near-identity 32x32 matrices via Newton-Schulz
//        X' = 1.5X - 0.5*X*X^T*X, 5 iterations, run entirely on MFMA
//        (split-bf16 hi/lo, f32 accumulate), zero LDS / zero cross-lane:
//        for mfma_f32_32x32x16_bf16 the per-lane A/B k-set {4g+8m+(0..3)}
//        equals the C/D row-set (q&3)+8*(q>>2)+4g, so C/D output of one
//        product IS the A/B fragment of the next (N symmetric).
// base/conn/gen: coalesced gathers.

#define NMAT  32768
#define NITER 5

typedef __attribute__((ext_vector_type(8)))  __bf16 bf16x8;
typedef __attribute__((ext_vector_type(16))) float  f32x16;

__device__ __forceinline__ f32x16 mfma32(bf16x8 a, bf16x8 b, f32x16 c) {
    return __builtin_amdgcn_mfma_f32_32x32x16_bf16(a, b, c, 0, 0, 0);
}

__device__ __forceinline__ f32x16 zero16() {
    f32x16 v;
    #pragma unroll
    for (int q = 0; q < 16; ++q) v[q] = 0.0f;
    return v;
}

// Split 8 consecutive f32 (arr[base..base+7]) into bf16 hi + lo fragments.
#define SPLIT8(arr, base, H, L)                         \
    do {                                                \
        _Pragma("unroll")                               \
        for (int _j = 0; _j < 8; ++_j) {                \
            float _x = (arr)[(base) + _j];              \
            __bf16 _hb = (__bf16)_x;                    \
            (H)[_j] = _hb;                              \
            (L)[_j] = (__bf16)(_x - (float)_hb);        \
        }                                               \
    } while (0)

__global__ __launch_bounds__(256) void polar_kernel(
    const int* __restrict__ tokens,
    const float* __restrict__ fiber_w,
    float* __restrict__ out_fiber)
{
    const int wave = threadIdx.x >> 6;
    const int lane = threadIdx.x & 63;
    const int mat  = blockIdx.x * 4 + wave;   // one 32x32 matrix per wave
    const int rc   = lane & 31;               // A-frag row / B- & CD-frag col
    const int g    = lane >> 5;               // lane group

    const int tok = tokens[mat];
    const float* src0 = fiber_w + (size_t)tok * 1024;

    // ---- A-copy (row-slab): X[rc][k], k in {4g,8+4g,16+4g,24+4g}+0..3 ----
    const float* arow = src0 + rc * 32 + 4 * g;
    float4 a0 = *(const float4*)(arow + 0);
    float4 a1 = *(const float4*)(arow + 8);
    float4 a2 = *(const float4*)(arow + 16);
    float4 a3 = *(const float4*)(arow + 24);
    float aL[16] = {a0.x,a0.y,a0.z,a0.w, a1.x,a1.y,a1.z,a1.w,
                    a2.x,a2.y,a2.z,a2.w, a3.x,a3.y,a3.z,a3.w};

    // ---- B-copy (col-slab): X[k][rc], same k-set; each scalar load is
    //      line-coalesced across the wave (lanes 0..31 span one 128B row) ----
    float bL[16];
    #pragma unroll
    for (int i2 = 0; i2 < 2; ++i2) {
        #pragma unroll
        for (int j = 0; j < 8; ++j) {
            int k = 16 * i2 + 4 * g + 8 * (j >> 2) + (j & 3);
            bL[8 * i2 + j] = src0[k * 32 + rc];
        }
    }

    bf16x8 Ah0, Ah1, Al0, Al1, Bh0, Bh1, Bl0, Bl1;
    SPLIT8(aL, 0, Ah0, Al0);  SPLIT8(aL, 8, Ah1, Al1);
    SPLIT8(bL, 0, Bh0, Bl0);  SPLIT8(bL, 8, Bh1, Bl1);

    // diagonal mask for N = 1.5I - 0.5P in C/D layout
    float dv[16];
    #pragma unroll
    for (int q = 0; q < 16; ++q)
        dv[q] = (((q & 3) + 8 * (q >> 2) + 4 * g) == rc) ? 1.5f : 0.0f;

    f32x16 y;

    #pragma unroll
    for (int iter = 0; iter < NITER; ++iter) {
        // ---- P = X^T X  (A-frag(X^T) == B-frag(X) == B-copy regs) ----
        f32x16 p = zero16();
        p = mfma32(Bh0, Bh0, p);  p = mfma32(Bh1, Bh1, p);
        p = mfma32(Bh0, Bl0, p);  p = mfma32(Bh1, Bl1, p);
        p = mfma32(Bl0, Bh0, p);  p = mfma32(Bl1, Bh1, p);

        // ---- N = 1.5I - 0.5P  (C/D layout == A-frag(N) == B-frag(N)) ----
        float nv[16];
        #pragma unroll
        for (int q = 0; q < 16; ++q)
            nv[q] = __builtin_fmaf(-0.5f, p[q], dv[q]);
        bf16x8 Nh0, Nh1, Nl0, Nl1;
        SPLIT8(nv, 0, Nh0, Nl0);  SPLIT8(nv, 8, Nh1, Nl1);

        // ---- Y = N * X^T = (X')^T  -> row-slab of X' (next A-copy) ----
        y = zero16();
        y = mfma32(Nh0, Ah0, y);  y = mfma32(Nh1, Ah1, y);
        y = mfma32(Nh0, Al0, y);  y = mfma32(Nh1, Al1, y);
        y = mfma32(Nl0, Ah0, y);  y = mfma32(Nl1, Ah1, y);

        if (iter < NITER - 1) {
            // ---- Z = X * N -> col-slab of X' (next B-copy) ----
            f32x16 z = zero16();
            z = mfma32(Ah0, Nh0, z);  z = mfma32(Ah1, Nh1, z);
            z = mfma32(Ah0, Nl0, z);  z = mfma32(Ah1, Nl1, z);
            z = mfma32(Al0, Nh0, z);  z = mfma32(Al1, Nh1, z);
            SPLIT8(z, 0, Bh0, Bl0);  SPLIT8(z, 8, Bh1, Bl1);
            SPLIT8(y, 0, Ah0, Al0);  SPLIT8(y, 8, Ah1, Al1);
        }
    }

    // y[q] = X5[rc][ (q&3)+8*(q>>2)+4g ] : 4 float4 stores, row rc
    float* dst = out_fiber + (size_t)mat * 1024 + rc * 32 + 4 * g;
    *(float4*)(dst +  0) = make_float4(y[0],  y[1],  y[2],  y[3]);
    *(float4*)(dst +  8) = make_float4(y[4],  y[5],  y[6],  y[7]);
    *(float4*)(dst + 16) = make_float4(y[8],  y[9],  y[10], y[11]);
    *(float4*)(dst + 24) = make_float4(y[12], y[13], y[14], y[15]);
}

// base gather: one wave per output row (512 floats = 128 float4), token is
// wave-uniform -> scalar load; fully coalesced 1KB vector transactions.
__global__ __launch_bounds__(256) void base_gather(
    const int*    __restrict__ tokens,
    const float4* __restrict__ base_w,
    float4*       __restrict__ out)
{
    const int wave = threadIdx.x >> 6;
    const int lane = threadIdx.x & 63;
    const int row  = blockIdx.x * 4 + wave;          // 0..32767
    const int tok  = tokens[row];
    const float4* src = base_w + (size_t)tok * 128;
    float4*       dst = out    + (size_t)row * 128;
    dst[lane]      = src[lane];
    dst[lane + 64] = src[lane + 64];
}

// connection gather + generators passthrough (contiguous in out).
__global__ __launch_bounds__(256) void tail_gather(
    const int*    __restrict__ tokens,
    const float4* __restrict__ conn_w,
    const float4* __restrict__ gens,
    float4*       __restrict__ out)       // points at conn section
{
    const int i = blockIdx.x * 256 + threadIdx.x;
    if (i < 65536) {
        out[i] = conn_w[(size_t)tokens[i >> 1] * 2 + (i & 1)];
    } else if (i < 65536 + 2048) {
        out[i] = gens[i - 65536];
    }
}

extern "C" void kernel_launch(void* const* d_in, const int* in_sizes, int n_in,
                              void* d_out, int out_size, void* d_ws, size_t ws_size,
                              hipStream_t stream) {
    const int*   tokens  = (const int*)  d_in[0];
    const float* base_w  = (const float*)d_in[1];
    const float* fiber_w = (const float*)d_in[2];
    const float* conn_w  = (const float*)d_in[3];
    const float* gens    = (const float*)d_in[4];
    float* out = (float*)d_out;

    polar_kernel<<<NMAT / 4, 256, 0, stream>>>(tokens, fiber_w, out + 16777216);
    base_gather<<<NMAT / 4, 256, 0, stream>>>(
        tokens, reinterpret_cast<const float4*>(base_w),
        reinterpret_cast<float4*>(out));
    tail_gather<<<264, 256, 0, stream>>>(
        tokens, reinterpret_cast<const float4*>(conn_w),
        reinterpret_cast<const float4*>(gens),
        reinterpret_cast<float4*>(out) + 12582912);
}